// Round 7
// baseline (127.242 us; speedup 1.0000x reference)
//
#include <hip/hip_runtime.h>
#include <math.h>

#define NB 1024
#define IC 3
#define HW 32
#define GCH 16
#define ECH 32
#define NE 8
#define NC 100

// One block per sample. Pixel-SERIAL / channel-inner design: each thread
// owns 4 pixels processed one at a time, so only a 27-float patch is live
// (fits the allocator's preferred <=64 VGPR operating point -- rounds 2-6
// proved it refuses more and either rematerializes loads or spills).
// Per-channel pooled partials accumulate in LDS (own row per thread,
// stride 33 -> 2-way banking = free).
__global__ __launch_bounds__(256) void moe_fused_kernel(
    const float* __restrict__ x,     // [1024,3,32,32]
    const float* __restrict__ gcw,   // [16,3,3,3]
    const float* __restrict__ gcb,   // [16]
    const float* __restrict__ glw,   // [8,16]
    const float* __restrict__ glb,   // [8]
    const float* __restrict__ ecw,   // [8,32,3,3,3]
    const float* __restrict__ ecb,   // [8,32]
    const float* __restrict__ elw,   // [8,100,32]
    const float* __restrict__ elb,   // [8,100]
    float* __restrict__ out_final,   // [1024,100]
    float* __restrict__ out_w)       // [1024,8]
{
    __shared__ float pred[256][33];  // per-thread channel partials
    __shared__ float red2[4][ECH];
    __shared__ float pg[GCH];
    __shared__ float pe[ECH];
    __shared__ int s_best;

    const int t = threadIdx.x;
    const int b = blockIdx.x;
    const int lane = t & 63;
    const int wid = t >> 6;
    const float* xb = x + (size_t)b * (IC * HW * HW);

    // ---------------- phase 1: gate conv + pool ----------------
    #pragma unroll
    for (int c = 0; c < GCH; ++c) pred[t][c] = 0.f;
    __syncthreads();   // (cheap; keeps pred init ordered before rmw)

    #pragma unroll 1
    for (int pp = 0; pp < 4; ++pp) {
        const int p = t + pp * 256;
        const int py = p >> 5, px = p & 31;

        float patch[IC][3][3];
        #pragma unroll
        for (int ci = 0; ci < IC; ++ci) {
            const float* xc = xb + ci * (HW * HW);
            #pragma unroll
            for (int ky = 0; ky < 3; ++ky) {
                int row = py + ky - 1;
                bool rok = (row >= 0) && (row < HW);
                const float* xrow = xc + (rok ? row : 0) * HW;
                #pragma unroll
                for (int kx = 0; kx < 3; ++kx) {
                    int col = px + kx - 1;
                    bool ok = rok && (col >= 0) && (col < HW);
                    float v = xrow[(col >= 0 && col < HW) ? col : px];
                    patch[ci][ky][kx] = ok ? v : 0.f;
                }
            }
        }

        #pragma unroll
        for (int c = 0; c < GCH; ++c) {
            const float* w = gcw + c * 27;          // uniform -> s_load
            float s0 = 0.f, s1 = 0.f, s2 = 0.f;     // 3-way ILP
            #pragma unroll
            for (int ky = 0; ky < 3; ++ky)
                #pragma unroll
                for (int kx = 0; kx < 3; ++kx) {
                    s0 += patch[0][ky][kx] * w[0 * 9 + ky * 3 + kx];
                    s1 += patch[1][ky][kx] * w[1 * 9 + ky * 3 + kx];
                    s2 += patch[2][ky][kx] * w[2 * 9 + ky * 3 + kx];
                }
            float v = fmaxf(s0 + s1 + s2 + gcb[c], 0.f);
            pred[t][c] += v;
        }
    }
    __syncthreads();

    // transpose-reduce 256 rows -> pg[16]
    {
        const int c = t & 15, j = t >> 4;
        float v = 0.f;
        #pragma unroll
        for (int i = 0; i < 16; ++i) v += pred[j * 16 + i][c];
        v += __shfl_xor(v, 16);
        v += __shfl_xor(v, 32);
        if (lane < 16) red2[wid][lane] = v;
    }
    __syncthreads();
    if (t < GCH)
        pg[t] = (red2[0][t] + red2[1][t] + red2[2][t] + red2[3][t]) * (1.f / 1024.f);
    __syncthreads();

    // ---- gate linear + softmax + argmax (lanes 0..7) ----
    if (t < NE) {
        float acc = glb[t];
        #pragma unroll
        for (int c = 0; c < GCH; ++c) acc += pg[c] * glw[t * GCH + c];
        float m = acc;
        #pragma unroll
        for (int off = 1; off < NE; off <<= 1) m = fmaxf(m, __shfl_xor(m, off));
        float ex = expf(acc - m);
        float s = ex;
        #pragma unroll
        for (int off = 1; off < NE; off <<= 1) s += __shfl_xor(s, off);
        out_w[(size_t)b * NE + t] = ex / s;
        float mv = acc; int mi = t;
        #pragma unroll
        for (int off = 1; off < NE; off <<= 1) {
            float ov = __shfl_xor(mv, off);
            int   oi = __shfl_xor(mi, off);
            if (ov > mv || (ov == mv && oi < mi)) { mv = ov; mi = oi; }
        }
        if (t == 0) s_best = mi;
    }

    // ---------------- phase 2: selected expert conv + pool ----------------
    #pragma unroll
    for (int c = 0; c < ECH; ++c) pred[t][c] = 0.f;
    __syncthreads();
    const int e = __builtin_amdgcn_readfirstlane(s_best);
    const float* ewp = ecw + (size_t)e * (ECH * 27);
    const float* ebp = ecb + (size_t)e * ECH;

    #pragma unroll 1
    for (int pp = 0; pp < 4; ++pp) {
        const int p = t + pp * 256;
        const int py = p >> 5, px = p & 31;

        float patch[IC][3][3];
        #pragma unroll
        for (int ci = 0; ci < IC; ++ci) {
            const float* xc = xb + ci * (HW * HW);
            #pragma unroll
            for (int ky = 0; ky < 3; ++ky) {
                int row = py + ky - 1;
                bool rok = (row >= 0) && (row < HW);
                const float* xrow = xc + (rok ? row : 0) * HW;
                #pragma unroll
                for (int kx = 0; kx < 3; ++kx) {
                    int col = px + kx - 1;
                    bool ok = rok && (col >= 0) && (col < HW);
                    float v = xrow[(col >= 0 && col < HW) ? col : px];
                    patch[ci][ky][kx] = ok ? v : 0.f;
                }
            }
        }

        #pragma unroll
        for (int c = 0; c < ECH; ++c) {
            const float* w = ewp + c * 27;          // uniform -> s_load
            float s0 = 0.f, s1 = 0.f, s2 = 0.f;
            #pragma unroll
            for (int ky = 0; ky < 3; ++ky)
                #pragma unroll
                for (int kx = 0; kx < 3; ++kx) {
                    s0 += patch[0][ky][kx] * w[0 * 9 + ky * 3 + kx];
                    s1 += patch[1][ky][kx] * w[1 * 9 + ky * 3 + kx];
                    s2 += patch[2][ky][kx] * w[2 * 9 + ky * 3 + kx];
                }
            float v = fmaxf(s0 + s1 + s2 + ebp[c], 0.f);
            pred[t][c] += v;
        }
    }
    __syncthreads();

    // transpose-reduce 256 rows -> pe[32]
    {
        const int c = t & 31, j = t >> 5;
        float v = 0.f;
        #pragma unroll
        for (int i = 0; i < 32; ++i) v += pred[j * 32 + i][c];
        v += __shfl_xor(v, 32);
        if (lane < 32) red2[wid][lane] = v;
    }
    __syncthreads();
    if (t < ECH)
        pe[t] = (red2[0][t] + red2[1][t] + red2[2][t] + red2[3][t]) * (1.f / 1024.f);
    __syncthreads();

    // ---- expert linear: 100 outputs ----
    if (t < NC) {
        const float* lw = elw + ((size_t)e * NC + t) * ECH;
        float acc = elb[e * NC + t];
        #pragma unroll
        for (int c = 0; c < ECH; ++c) acc += pe[c] * lw[c];
        out_final[(size_t)b * NC + t] = acc;
    }
}

extern "C" void kernel_launch(void* const* d_in, const int* in_sizes, int n_in,
                              void* d_out, int out_size, void* d_ws, size_t ws_size,
                              hipStream_t stream) {
    const float* x   = (const float*)d_in[0];
    const float* gcw = (const float*)d_in[1];
    const float* gcb = (const float*)d_in[2];
    const float* glw = (const float*)d_in[3];
    const float* glb = (const float*)d_in[4];
    const float* ecw = (const float*)d_in[5];
    const float* ecb = (const float*)d_in[6];
    const float* elw = (const float*)d_in[7];
    const float* elb = (const float*)d_in[8];

    float* out_final = (float*)d_out;             // [1024,100]
    float* out_w     = (float*)d_out + NB * NC;   // [1024,8]

    hipLaunchKernelGGL(moe_fused_kernel, dim3(NB), dim3(256), 0, stream,
                       x, gcw, gcb, glw, glb, ecw, ecb, elw, elb,
                       out_final, out_w);
}

// Round 8
// 64.355 us; speedup vs baseline: 1.9772x; 1.9772x over previous
//
#include <hip/hip_runtime.h>
#include <math.h>

#define NB 1024
#define IC 3
#define HW 32
#define GCH 16
#define ECH 32
#define NE 8
#define NC 100

// One block per sample, 2 pixels/thread x 2 sequential groups.
// Patch = 3x3x4 = 36 floats -> live set ~50 VGPRs, INSIDE the allocator's
// proven <=64-VGPR operating point (rounds 4-6 showed 4-px tiling needed ~66
// live -> forced load rematerialization; forcing more regs -> scratch spill).
// Weights stay on the hoisted s_load path (per channel-pair), patch operands
// stay in VGPRs -> inner loop is pure v_fmac with SGPR weight operands.
__global__ __launch_bounds__(256) void moe_fused_kernel(
    const float* __restrict__ x,     // [1024,3,32,32]
    const float* __restrict__ gcw,   // [16,3,3,3]
    const float* __restrict__ gcb,   // [16]
    const float* __restrict__ glw,   // [8,16]
    const float* __restrict__ glb,   // [8]
    const float* __restrict__ ecw,   // [8,32,3,3,3]
    const float* __restrict__ ecb,   // [8,32]
    const float* __restrict__ elw,   // [8,100,32]
    const float* __restrict__ elb,   // [8,100]
    float* __restrict__ out_final,   // [1024,100]
    float* __restrict__ out_w)       // [1024,8]
{
    __shared__ float red[4][ECH];    // per-wave per-channel pooled partials
    __shared__ float pg[GCH];
    __shared__ float pe[ECH];
    __shared__ int s_best;

    const int t = threadIdx.x;
    const int b = blockIdx.x;
    const int lane = t & 63;
    const int wid = t >> 6;
    const float* xb = x + (size_t)b * (IC * HW * HW);

    if (t < 4 * ECH) ((float*)red)[t] = 0.f;
    __syncthreads();

    // ================= gate phase: conv + relu + pool =================
    #pragma unroll 1
    for (int g = 0; g < 2; ++g) {
        const int P = g * 512 + t * 2;     // pixel pair base
        const int py = P >> 5, px0 = P & 31;   // px0 even

        // 3x3x(4 cols) patch: cols px0-1 .. px0+2
        float pa[IC][3][4];
        #pragma unroll
        for (int ci = 0; ci < IC; ++ci) {
            const float* xc = xb + ci * (HW * HW);
            #pragma unroll
            for (int ky = 0; ky < 3; ++ky) {
                int row = py + ky - 1;
                bool rok = (row >= 0) && (row < HW);
                const float* xrow = xc + (rok ? row : 0) * HW;
                float  l = xrow[px0 > 0 ? px0 - 1 : 0];
                float2 m = *(const float2*)(xrow + px0);    // 8B-aligned
                float  r = xrow[px0 + 2 < HW ? px0 + 2 : HW - 1];
                pa[ci][ky][0] = (rok && px0 > 0) ? l : 0.f;
                pa[ci][ky][1] = rok ? m.x : 0.f;
                pa[ci][ky][2] = rok ? m.y : 0.f;
                pa[ci][ky][3] = (rok && (px0 + 2 < HW)) ? r : 0.f;
            }
        }

        #pragma unroll 2
        for (int c = 0; c < GCH; ++c) {
            const float* w = gcw + c * 27;   // uniform -> s_load, hoisted/ch
            float p0 = 0.f, p1 = 0.f;
            #pragma unroll
            for (int ci = 0; ci < IC; ++ci)
                #pragma unroll
                for (int ky = 0; ky < 3; ++ky)
                    #pragma unroll
                    for (int kx = 0; kx < 3; ++kx) {
                        float wv = w[(ci * 3 + ky) * 3 + kx];
                        p0 += pa[ci][ky][kx + 0] * wv;
                        p1 += pa[ci][ky][kx + 1] * wv;
                    }
            float bias = gcb[c];
            float v = fmaxf(p0 + bias, 0.f) + fmaxf(p1 + bias, 0.f);
            #pragma unroll
            for (int off = 1; off < 64; off <<= 1) v += __shfl_xor(v, off);
            if (lane == 0) red[wid][c] += v;
        }
    }
    __syncthreads();
    if (t < GCH)
        pg[t] = (red[0][t] + red[1][t] + red[2][t] + red[3][t]) * (1.f / 1024.f);
    __syncthreads();

    // ---- gate linear + softmax + argmax (lanes 0..7); re-zero red ----
    if (t < NE) {
        float acc = glb[t];
        #pragma unroll
        for (int c = 0; c < GCH; ++c) acc += pg[c] * glw[t * GCH + c];
        float m = acc;
        #pragma unroll
        for (int off = 1; off < NE; off <<= 1) m = fmaxf(m, __shfl_xor(m, off));
        float ex = expf(acc - m);
        float s = ex;
        #pragma unroll
        for (int off = 1; off < NE; off <<= 1) s += __shfl_xor(s, off);
        out_w[(size_t)b * NE + t] = ex / s;
        float mv = acc; int mi = t;
        #pragma unroll
        for (int off = 1; off < NE; off <<= 1) {
            float ov = __shfl_xor(mv, off);
            int   oi = __shfl_xor(mi, off);
            if (ov > mv || (ov == mv && oi < mi)) { mv = ov; mi = oi; }
        }
        if (t == 0) s_best = mi;
    }
    if (t >= 64 && t < 64 + 4 * ECH) ((float*)red)[t - 64] = 0.f;  // wave1/2: re-zero
    __syncthreads();
    const int e = __builtin_amdgcn_readfirstlane(s_best);

    // ================= expert phase: conv + relu + pool =================
    const float* ewp = ecw + (size_t)e * (ECH * 27);
    const float* ebp = ecb + (size_t)e * ECH;
    #pragma unroll 1
    for (int g = 0; g < 2; ++g) {
        const int P = g * 512 + t * 2;
        const int py = P >> 5, px0 = P & 31;

        float pa[IC][3][4];
        #pragma unroll
        for (int ci = 0; ci < IC; ++ci) {
            const float* xc = xb + ci * (HW * HW);
            #pragma unroll
            for (int ky = 0; ky < 3; ++ky) {
                int row = py + ky - 1;
                bool rok = (row >= 0) && (row < HW);
                const float* xrow = xc + (rok ? row : 0) * HW;
                float  l = xrow[px0 > 0 ? px0 - 1 : 0];
                float2 m = *(const float2*)(xrow + px0);
                float  r = xrow[px0 + 2 < HW ? px0 + 2 : HW - 1];
                pa[ci][ky][0] = (rok && px0 > 0) ? l : 0.f;
                pa[ci][ky][1] = rok ? m.x : 0.f;
                pa[ci][ky][2] = rok ? m.y : 0.f;
                pa[ci][ky][3] = (rok && (px0 + 2 < HW)) ? r : 0.f;
            }
        }

        #pragma unroll 2
        for (int c = 0; c < ECH; ++c) {
            const float* w = ewp + c * 27;   // uniform -> s_load
            float p0 = 0.f, p1 = 0.f;
            #pragma unroll
            for (int ci = 0; ci < IC; ++ci)
                #pragma unroll
                for (int ky = 0; ky < 3; ++ky)
                    #pragma unroll
                    for (int kx = 0; kx < 3; ++kx) {
                        float wv = w[(ci * 3 + ky) * 3 + kx];
                        p0 += pa[ci][ky][kx + 0] * wv;
                        p1 += pa[ci][ky][kx + 1] * wv;
                    }
            float bias = ebp[c];
            float v = fmaxf(p0 + bias, 0.f) + fmaxf(p1 + bias, 0.f);
            #pragma unroll
            for (int off = 1; off < 64; off <<= 1) v += __shfl_xor(v, off);
            if (lane == 0) red[wid][c] += v;
        }
    }
    __syncthreads();
    if (t < ECH)
        pe[t] = (red[0][t] + red[1][t] + red[2][t] + red[3][t]) * (1.f / 1024.f);
    __syncthreads();

    // ---- expert linear: 100 outputs ----
    if (t < NC) {
        const float* lw = elw + ((size_t)e * NC + t) * ECH;
        float acc = elb[e * NC + t];
        #pragma unroll
        for (int c = 0; c < ECH; ++c) acc += pe[c] * lw[c];
        out_final[(size_t)b * NC + t] = acc;
    }
}

extern "C" void kernel_launch(void* const* d_in, const int* in_sizes, int n_in,
                              void* d_out, int out_size, void* d_ws, size_t ws_size,
                              hipStream_t stream) {
    const float* x   = (const float*)d_in[0];
    const float* gcw = (const float*)d_in[1];
    const float* gcb = (const float*)d_in[2];
    const float* glw = (const float*)d_in[3];
    const float* glb = (const float*)d_in[4];
    const float* ecw = (const float*)d_in[5];
    const float* ecb = (const float*)d_in[6];
    const float* elw = (const float*)d_in[7];
    const float* elb = (const float*)d_in[8];

    float* out_final = (float*)d_out;             // [1024,100]
    float* out_w     = (float*)d_out + NB * NC;   // [1024,8]

    hipLaunchKernelGGL(moe_fused_kernel, dim3(NB), dim3(256), 0, stream,
                       x, gcw, gcb, glw, glb, ecw, ecb, elw, elb,
                       out_final, out_w);
}

// Round 9
// 40.196 us; speedup vs baseline: 3.1655x; 1.6010x over previous
//
#include <hip/hip_runtime.h>
#include <math.h>

#define NB 1024
#define IC 3
#define HW 32
#define GCH 16
#define ECH 32
#define NE 8
#define NC 100

// Shifted-padded LDS image: xs[ci][y][col], col j holds x[y-1][j-1]
// (zero border), row length 36 floats = 144 B (16B-aligned at every px0).
// Per (ci,ky): ONE float4 + ONE float2 aligned LDS read -> 6 operands ->
// 12 FMAs per channel (4 px x 3 kx). Channel-group of 8 unrolled inner;
// (ci,ky) loops unroll-1 so only 6 operand floats are live at a time
// (rounds 4-8 proved the allocator refuses long-lived patches).
__global__ __launch_bounds__(256) void moe_fused_kernel(
    const float* __restrict__ x,     // [1024,3,32,32]
    const float* __restrict__ gcw,   // [16,3,3,3]
    const float* __restrict__ gcb,   // [16]
    const float* __restrict__ glw,   // [8,16]
    const float* __restrict__ glb,   // [8]
    const float* __restrict__ ecw,   // [8,32,3,3,3]
    const float* __restrict__ ecb,   // [8,32]
    const float* __restrict__ elw,   // [8,100,32]
    const float* __restrict__ elb,   // [8,100]
    float* __restrict__ out_final,   // [1024,100]
    float* __restrict__ out_w)       // [1024,8]
{
    __shared__ float xs[IC][34][36];
    __shared__ float pred[256][17];
    __shared__ float red2[4][16];
    __shared__ float pg[GCH];
    __shared__ float pe[ECH];
    __shared__ int s_best;

    const int t = threadIdx.x;
    const int b = blockIdx.x;
    const int lane = t & 63;
    const int wid = t >> 6;

    const int py = t >> 3;          // output row 0..31
    const int px0 = (t & 7) << 2;   // output col base 0,4,...,28

    // ---- stage x into shifted-padded LDS ----
    for (int i = t; i < IC * 34 * 36; i += 256) ((float*)xs)[i] = 0.f;
    __syncthreads();
    const float* xb = x + (size_t)b * (IC * HW * HW);
    for (int i = t; i < (IC * HW * HW) / 4; i += 256) {   // 768 float4s
        float4 v = ((const float4*)xb)[i];
        int ci = i >> 8, rem = i & 255, y = rem >> 3, x4 = (rem & 7) << 2;
        float* d = &xs[ci][y + 1][x4 + 1];
        d[0] = v.x; d[1] = v.y; d[2] = v.z; d[3] = v.w;
    }
    __syncthreads();

    // ---- conv8: 8 output channels, 4 px/thread, pooled partial -> pred ----
    auto conv8 = [&](const float* wb, const float* bp, int colbase) {
        float acc[8][4];
        #pragma unroll
        for (int c = 0; c < 8; ++c)
            acc[c][0] = acc[c][1] = acc[c][2] = acc[c][3] = 0.f;
        #pragma unroll 1
        for (int ci = 0; ci < IC; ++ci) {
            #pragma unroll 1
            for (int ky = 0; ky < 3; ++ky) {
                const float* row = &xs[ci][py + ky][0];
                float4 A  = *(const float4*)(row + px0);       // x[px0-1..px0+2]
                float2 Bv = *(const float2*)(row + px0 + 4);   // x[px0+3..px0+4]
                const float* ws = wb + (ci * 3 + ky) * 3;      // uniform
                #pragma unroll
                for (int c = 0; c < 8; ++c) {
                    float w0 = ws[c * 27 + 0];
                    float w1 = ws[c * 27 + 1];
                    float w2 = ws[c * 27 + 2];
                    acc[c][0] = fmaf(A.x, w0, fmaf(A.y,  w1, fmaf(A.z,  w2, acc[c][0])));
                    acc[c][1] = fmaf(A.y, w0, fmaf(A.z,  w1, fmaf(A.w,  w2, acc[c][1])));
                    acc[c][2] = fmaf(A.z, w0, fmaf(A.w,  w1, fmaf(Bv.x, w2, acc[c][2])));
                    acc[c][3] = fmaf(A.w, w0, fmaf(Bv.x, w1, fmaf(Bv.y, w2, acc[c][3])));
                }
            }
        }
        #pragma unroll
        for (int c = 0; c < 8; ++c) {
            float bias = bp[c];
            pred[t][colbase + c] =
                fmaxf(acc[c][0] + bias, 0.f) + fmaxf(acc[c][1] + bias, 0.f) +
                fmaxf(acc[c][2] + bias, 0.f) + fmaxf(acc[c][3] + bias, 0.f);
        }
    };

    // ---- bulk transpose-reduce of pred[256][0..15] -> dst[16] ----
    auto reduce16 = [&](float* dst) {
        const int c = t & 15, j = t >> 4;
        float v = 0.f;
        #pragma unroll
        for (int i = 0; i < 16; ++i) v += pred[j * 16 + i][c];
        v += __shfl_xor(v, 16);
        v += __shfl_xor(v, 32);
        if (lane < 16) red2[wid][lane] = v;
        __syncthreads();
        if (t < 16)
            dst[t] = (red2[0][t] + red2[1][t] + red2[2][t] + red2[3][t]) * (1.f / 1024.f);
        __syncthreads();
    };

    // ================= gate =================
    conv8(gcw, gcb, 0);
    conv8(gcw + 8 * 27, gcb + 8, 8);
    __syncthreads();
    reduce16(pg);

    if (t < NE) {
        float acc = glb[t];
        #pragma unroll
        for (int c = 0; c < GCH; ++c) acc += pg[c] * glw[t * GCH + c];
        float m = acc;
        #pragma unroll
        for (int off = 1; off < NE; off <<= 1) m = fmaxf(m, __shfl_xor(m, off));
        float ex = expf(acc - m);
        float s = ex;
        #pragma unroll
        for (int off = 1; off < NE; off <<= 1) s += __shfl_xor(s, off);
        out_w[(size_t)b * NE + t] = ex / s;
        float mv = acc; int mi = t;
        #pragma unroll
        for (int off = 1; off < NE; off <<= 1) {
            float ov = __shfl_xor(mv, off);
            int   oi = __shfl_xor(mi, off);
            if (ov > mv || (ov == mv && oi < mi)) { mv = ov; mi = oi; }
        }
        if (t == 0) s_best = mi;
    }
    __syncthreads();
    const int e = __builtin_amdgcn_readfirstlane(s_best);

    // ================= selected expert =================
    const float* ewp = ecw + (size_t)e * (ECH * 27);
    const float* ebp = ecb + (size_t)e * ECH;

    conv8(ewp, ebp, 0);
    conv8(ewp + 8 * 27, ebp + 8, 8);
    __syncthreads();
    reduce16(pe);

    conv8(ewp + 16 * 27, ebp + 16, 0);
    conv8(ewp + 24 * 27, ebp + 24, 8);
    __syncthreads();
    reduce16(pe + 16);

    // ---- expert linear: 100 outputs ----
    if (t < NC) {
        const float* lw = elw + ((size_t)e * NC + t) * ECH;
        float acc = elb[e * NC + t];
        #pragma unroll
        for (int c = 0; c < ECH; ++c) acc += pe[c] * lw[c];
        out_final[(size_t)b * NC + t] = acc;
    }
}

extern "C" void kernel_launch(void* const* d_in, const int* in_sizes, int n_in,
                              void* d_out, int out_size, void* d_ws, size_t ws_size,
                              hipStream_t stream) {
    const float* x   = (const float*)d_in[0];
    const float* gcw = (const float*)d_in[1];
    const float* gcb = (const float*)d_in[2];
    const float* glw = (const float*)d_in[3];
    const float* glb = (const float*)d_in[4];
    const float* ecw = (const float*)d_in[5];
    const float* ecb = (const float*)d_in[6];
    const float* elw = (const float*)d_in[7];
    const float* elb = (const float*)d_in[8];

    float* out_final = (float*)d_out;             // [1024,100]
    float* out_w     = (float*)d_out + NB * NC;   // [1024,8]

    hipLaunchKernelGGL(moe_fused_kernel, dim3(NB), dim3(256), 0, stream,
                       x, gcw, gcb, glw, glb, ecw, ecb, elw, elb,
                       out_final, out_w);
}

// Round 10
// 39.511 us; speedup vs baseline: 3.2204x; 1.0173x over previous
//
#include <hip/hip_runtime.h>
#include <math.h>

#define NB 1024
#define IC 3
#define HW 32
#define GCH 16
#define ECH 32
#define NE 8
#define NC 100

// Shifted-padded LDS image xs[ci][y][col] (col j holds x[y-1][j-1], zero
// border, row = 36 words). Conv reads are 3x ds_read_b64 per (ci,ky)
// (8B-aligned pairs -> 2-way bank aliasing = free; the r9 b128 pattern was
// ~8-way conflicted: 4.7M conflict cycles/dispatch). ky fully unrolled so
// 9 pair-loads pipeline under 288 FMAs per ci.
__global__ __launch_bounds__(256) void moe_fused_kernel(
    const float* __restrict__ x,     // [1024,3,32,32]
    const float* __restrict__ gcw,   // [16,3,3,3]
    const float* __restrict__ gcb,   // [16]
    const float* __restrict__ glw,   // [8,16]
    const float* __restrict__ glb,   // [8]
    const float* __restrict__ ecw,   // [8,32,3,3,3]
    const float* __restrict__ ecb,   // [8,32]
    const float* __restrict__ elw,   // [8,100,32]
    const float* __restrict__ elb,   // [8,100]
    float* __restrict__ out_final,   // [1024,100]
    float* __restrict__ out_w)       // [1024,8]
{
    __shared__ float xs[IC][34][36];
    __shared__ float pred[256][17];
    __shared__ float red2[4][16];
    __shared__ float pg[GCH];
    __shared__ float pe[ECH];
    __shared__ int s_best;

    const int t = threadIdx.x;
    const int b = blockIdx.x;
    const int lane = t & 63;
    const int wid = t >> 6;

    const int py = t >> 3;          // output row 0..31
    const int px0 = (t & 7) << 2;   // output col base 0,4,...,28

    // ---- stage x into shifted-padded LDS ----
    for (int i = t; i < IC * 34 * 36; i += 256) ((float*)xs)[i] = 0.f;
    __syncthreads();
    const float* xb = x + (size_t)b * (IC * HW * HW);
    for (int i = t; i < (IC * HW * HW) / 4; i += 256) {   // 768 float4s
        float4 v = ((const float4*)xb)[i];
        int ci = i >> 8, rem = i & 255, y = rem >> 3, x4 = (rem & 7) << 2;
        float* d = &xs[ci][y + 1][x4 + 1];
        d[0] = v.x; d[1] = v.y; d[2] = v.z; d[3] = v.w;
    }
    __syncthreads();

    // ---- conv8: 8 output channels, 4 px/thread, pooled partial -> pred ----
    auto conv8 = [&](const float* wb, const float* bp, int colbase) {
        float acc[8][4];
        #pragma unroll
        for (int c = 0; c < 8; ++c)
            acc[c][0] = acc[c][1] = acc[c][2] = acc[c][3] = 0.f;
        #pragma unroll 1
        for (int ci = 0; ci < IC; ++ci) {
            // all 9 operand-pairs of this ci issued together (pipelined)
            float2 P[3][3];
            #pragma unroll
            for (int ky = 0; ky < 3; ++ky) {
                const float* row = &xs[ci][py + ky][0];
                P[ky][0] = *(const float2*)(row + px0);
                P[ky][1] = *(const float2*)(row + px0 + 2);
                P[ky][2] = *(const float2*)(row + px0 + 4);
            }
            #pragma unroll
            for (int ky = 0; ky < 3; ++ky) {
                const float a0 = P[ky][0].x, a1 = P[ky][0].y;
                const float a2 = P[ky][1].x, a3 = P[ky][1].y;
                const float a4 = P[ky][2].x, a5 = P[ky][2].y;
                const float* ws = wb + (ci * 3 + ky) * 3;   // uniform -> s_load
                #pragma unroll
                for (int c = 0; c < 8; ++c) {
                    float w0 = ws[c * 27 + 0];
                    float w1 = ws[c * 27 + 1];
                    float w2 = ws[c * 27 + 2];
                    acc[c][0] = fmaf(a0, w0, fmaf(a1, w1, fmaf(a2, w2, acc[c][0])));
                    acc[c][1] = fmaf(a1, w0, fmaf(a2, w1, fmaf(a3, w2, acc[c][1])));
                    acc[c][2] = fmaf(a2, w0, fmaf(a3, w1, fmaf(a4, w2, acc[c][2])));
                    acc[c][3] = fmaf(a3, w0, fmaf(a4, w1, fmaf(a5, w2, acc[c][3])));
                }
            }
        }
        #pragma unroll
        for (int c = 0; c < 8; ++c) {
            float bias = bp[c];
            pred[t][colbase + c] =
                fmaxf(acc[c][0] + bias, 0.f) + fmaxf(acc[c][1] + bias, 0.f) +
                fmaxf(acc[c][2] + bias, 0.f) + fmaxf(acc[c][3] + bias, 0.f);
        }
    };

    // ---- bulk transpose-reduce of pred[256][0..15] -> dst[16] ----
    auto reduce16 = [&](float* dst) {
        const int c = t & 15, j = t >> 4;
        float v = 0.f;
        #pragma unroll
        for (int i = 0; i < 16; ++i) v += pred[j * 16 + i][c];
        v += __shfl_xor(v, 16);
        v += __shfl_xor(v, 32);
        if (lane < 16) red2[wid][lane] = v;
        __syncthreads();
        if (t < 16)
            dst[t] = (red2[0][t] + red2[1][t] + red2[2][t] + red2[3][t]) * (1.f / 1024.f);
        __syncthreads();
    };

    // ================= gate =================
    conv8(gcw, gcb, 0);
    conv8(gcw + 8 * 27, gcb + 8, 8);
    __syncthreads();
    reduce16(pg);

    if (t < NE) {
        float acc = glb[t];
        #pragma unroll
        for (int c = 0; c < GCH; ++c) acc += pg[c] * glw[t * GCH + c];
        float m = acc;
        #pragma unroll
        for (int off = 1; off < NE; off <<= 1) m = fmaxf(m, __shfl_xor(m, off));
        float ex = expf(acc - m);
        float s = ex;
        #pragma unroll
        for (int off = 1; off < NE; off <<= 1) s += __shfl_xor(s, off);
        out_w[(size_t)b * NE + t] = ex / s;
        float mv = acc; int mi = t;
        #pragma unroll
        for (int off = 1; off < NE; off <<= 1) {
            float ov = __shfl_xor(mv, off);
            int   oi = __shfl_xor(mi, off);
            if (ov > mv || (ov == mv && oi < mi)) { mv = ov; mi = oi; }
        }
        if (t == 0) s_best = mi;
    }
    __syncthreads();
    const int e = __builtin_amdgcn_readfirstlane(s_best);

    // ================= selected expert =================
    const float* ewp = ecw + (size_t)e * (ECH * 27);
    const float* ebp = ecb + (size_t)e * ECH;

    conv8(ewp, ebp, 0);
    conv8(ewp + 8 * 27, ebp + 8, 8);
    __syncthreads();
    reduce16(pe);

    conv8(ewp + 16 * 27, ebp + 16, 0);
    conv8(ewp + 24 * 27, ebp + 24, 8);
    __syncthreads();
    reduce16(pe + 16);

    // ---- expert linear: 100 outputs ----
    if (t < NC) {
        const float* lw = elw + ((size_t)e * NC + t) * ECH;
        float acc = elb[e * NC + t];
        #pragma unroll
        for (int c = 0; c < ECH; ++c) acc += pe[c] * lw[c];
        out_final[(size_t)b * NC + t] = acc;
    }
}

extern "C" void kernel_launch(void* const* d_in, const int* in_sizes, int n_in,
                              void* d_out, int out_size, void* d_ws, size_t ws_size,
                              hipStream_t stream) {
    const float* x   = (const float*)d_in[0];
    const float* gcw = (const float*)d_in[1];
    const float* gcb = (const float*)d_in[2];
    const float* glw = (const float*)d_in[3];
    const float* glb = (const float*)d_in[4];
    const float* ecw = (const float*)d_in[5];
    const float* ecb = (const float*)d_in[6];
    const float* elw = (const float*)d_in[7];
    const float* elb = (const float*)d_in[8];

    float* out_final = (float*)d_out;             // [1024,100]
    float* out_w     = (float*)d_out + NB * NC;   // [1024,8]

    hipLaunchKernelGGL(moe_fused_kernel, dim3(NB), dim3(256), 0, stream,
                       x, gcw, gcb, glw, glb, ecw, ecb, elw, elb,
                       out_final, out_w);
}

// Round 11
// 39.338 us; speedup vs baseline: 3.2346x; 1.0044x over previous
//
#include <hip/hip_runtime.h>
#include <math.h>

#define NB 1024
#define IC 3
#define HW 32
#define GCH 16
#define ECH 32
#define NE 8
#define NC 100

// Rotation-swizzled LDS image: row stride 32 words (all rows base-bank 0),
// per-row rotation phys = (px + 2*(sr&15)) & 31. Conv reads = 4x ds_read_b64
// per (ci,ky); bank-pair index = (2i + rowgrp + c) mod 16 -> exactly 4 lanes
// per bank-pair = conflict-free (r10's stride-36 layout was 8 lanes/pair,
// 5.6M conflict cycles/dispatch ~= 9us of LDS pipe). Border rows sr=0/33 are
// zeroed; column edges masked by cndmask. The 12 conv addresses are
// precomputed once and reused across all 6 conv passes (ci via literal off).
__global__ __launch_bounds__(256) void moe_fused_kernel(
    const float* __restrict__ x,     // [1024,3,32,32]
    const float* __restrict__ gcw,   // [16,3,3,3]
    const float* __restrict__ gcb,   // [16]
    const float* __restrict__ glw,   // [8,16]
    const float* __restrict__ glb,   // [8]
    const float* __restrict__ ecw,   // [8,32,3,3,3]
    const float* __restrict__ ecb,   // [8,32]
    const float* __restrict__ elw,   // [8,100,32]
    const float* __restrict__ elb,   // [8,100]
    float* __restrict__ out_final,   // [1024,100]
    float* __restrict__ out_w)       // [1024,8]
{
    __shared__ float xsw[IC * 34 * 32];   // rotated image, 13056 B
    __shared__ float pred[256][17];
    __shared__ float red2[4][16];
    __shared__ float pg[GCH];
    __shared__ float pe[ECH];
    __shared__ int s_best;

    const int t = threadIdx.x;
    const int b = blockIdx.x;
    const int lane = t & 63;
    const int wid = t >> 6;

    const int py = t >> 3;          // output row 0..31
    const int i8 = t & 7;
    const int px0 = i8 << 2;        // output col base 0,4,...,28

    // ---- zero border rows (sr=0,33) — disjoint from staged rows ----
    if (t < 192) {
        int ci = t / 64, r2 = (t & 63) >> 5, q = t & 31;   // 3ci x 2rows x 32
        xsw[ci * 1088 + (r2 == 0 ? 0 : 33) * 32 + q] = 0.f;
    }
    // ---- stage x with per-row rotation (rows sr=1..32) ----
    const float* xb = x + (size_t)b * (IC * HW * HW);
    for (int i = t; i < 768; i += 256) {
        float4 v = ((const float4*)xb)[i];
        int ci = i >> 8, rem = i & 255, row = rem >> 3, x4 = (rem & 7) << 2;
        int sr = row + 1, rot = 2 * (sr & 15);
        int base = ci * 1088 + sr * 32;
        *(float2*)&xsw[base + ((x4 + rot) & 31)]     = make_float2(v.x, v.y);
        *(float2*)&xsw[base + ((x4 + 2 + rot) & 31)] = make_float2(v.z, v.w);
    }
    __syncthreads();

    // ---- precompute the 12 conv read addresses (words, within ci plane 0) ----
    int idx[3][4];
    #pragma unroll
    for (int ky = 0; ky < 3; ++ky) {
        int sr = py + ky;                    // stored row (actual row py+ky-1)
        int rot = 2 * (sr & 15);
        int base = sr * 32;
        idx[ky][0] = base + ((px0 - 2 + rot) & 31);   // (.., o0)
        idx[ky][1] = base + ((px0     + rot) & 31);   // (o1, o2)
        idx[ky][2] = base + ((px0 + 2 + rot) & 31);   // (o3, o4)
        idx[ky][3] = base + ((px0 + 4 + rot) & 31);   // (o5, ..)
    }
    const bool mask0 = (i8 > 0);     // o0 valid unless px0==0
    const bool mask5 = (i8 < 7);     // o5 valid unless px0==28

    // ---- conv8: 8 output channels, 4 px/thread, pooled partial -> pred ----
    auto conv8 = [&](const float* wb, const float* bp, int colbase) {
        float acc[8][4];
        #pragma unroll
        for (int c = 0; c < 8; ++c)
            acc[c][0] = acc[c][1] = acc[c][2] = acc[c][3] = 0.f;
        #pragma unroll 1
        for (int ci = 0; ci < IC; ++ci) {
            const int cio = ci * 1088;
            #pragma unroll
            for (int ky = 0; ky < 3; ++ky) {
                float2 L0 = *(const float2*)&xsw[cio + idx[ky][0]];
                float2 L1 = *(const float2*)&xsw[cio + idx[ky][1]];
                float2 L2 = *(const float2*)&xsw[cio + idx[ky][2]];
                float2 L3 = *(const float2*)&xsw[cio + idx[ky][3]];
                float o0 = mask0 ? L0.y : 0.f;
                float o1 = L1.x, o2 = L1.y, o3 = L2.x, o4 = L2.y;
                float o5 = mask5 ? L3.x : 0.f;
                const float* ws = wb + (ci * 3 + ky) * 3;   // uniform -> s_load
                #pragma unroll
                for (int c = 0; c < 8; ++c) {
                    float w0 = ws[c * 27 + 0];
                    float w1 = ws[c * 27 + 1];
                    float w2 = ws[c * 27 + 2];
                    acc[c][0] = fmaf(o0, w0, fmaf(o1, w1, fmaf(o2, w2, acc[c][0])));
                    acc[c][1] = fmaf(o1, w0, fmaf(o2, w1, fmaf(o3, w2, acc[c][1])));
                    acc[c][2] = fmaf(o2, w0, fmaf(o3, w1, fmaf(o4, w2, acc[c][2])));
                    acc[c][3] = fmaf(o3, w0, fmaf(o4, w1, fmaf(o5, w2, acc[c][3])));
                }
            }
        }
        #pragma unroll
        for (int c = 0; c < 8; ++c) {
            float bias = bp[c];
            pred[t][colbase + c] =
                fmaxf(acc[c][0] + bias, 0.f) + fmaxf(acc[c][1] + bias, 0.f) +
                fmaxf(acc[c][2] + bias, 0.f) + fmaxf(acc[c][3] + bias, 0.f);
        }
    };

    // ---- bulk transpose-reduce of pred[256][0..15] -> dst[16] ----
    auto reduce16 = [&](float* dst) {
        const int c = t & 15, j = t >> 4;
        float v = 0.f;
        #pragma unroll
        for (int i = 0; i < 16; ++i) v += pred[j * 16 + i][c];
        v += __shfl_xor(v, 16);
        v += __shfl_xor(v, 32);
        if (lane < 16) red2[wid][lane] = v;
        __syncthreads();
        if (t < 16)
            dst[t] = (red2[0][t] + red2[1][t] + red2[2][t] + red2[3][t]) * (1.f / 1024.f);
        __syncthreads();
    };

    // ================= gate =================
    conv8(gcw, gcb, 0);
    conv8(gcw + 8 * 27, gcb + 8, 8);
    __syncthreads();
    reduce16(pg);

    if (t < NE) {
        float acc = glb[t];
        #pragma unroll
        for (int c = 0; c < GCH; ++c) acc += pg[c] * glw[t * GCH + c];
        float m = acc;
        #pragma unroll
        for (int off = 1; off < NE; off <<= 1) m = fmaxf(m, __shfl_xor(m, off));
        float ex = expf(acc - m);
        float s = ex;
        #pragma unroll
        for (int off = 1; off < NE; off <<= 1) s += __shfl_xor(s, off);
        out_w[(size_t)b * NE + t] = ex / s;
        float mv = acc; int mi = t;
        #pragma unroll
        for (int off = 1; off < NE; off <<= 1) {
            float ov = __shfl_xor(mv, off);
            int   oi = __shfl_xor(mi, off);
            if (ov > mv || (ov == mv && oi < mi)) { mv = ov; mi = oi; }
        }
        if (t == 0) s_best = mi;
    }
    __syncthreads();
    const int e = __builtin_amdgcn_readfirstlane(s_best);

    // ================= selected expert =================
    const float* ewp = ecw + (size_t)e * (ECH * 27);
    const float* ebp = ecb + (size_t)e * ECH;

    conv8(ewp, ebp, 0);
    conv8(ewp + 8 * 27, ebp + 8, 8);
    __syncthreads();
    reduce16(pe);

    conv8(ewp + 16 * 27, ebp + 16, 0);
    conv8(ewp + 24 * 27, ebp + 24, 8);
    __syncthreads();
    reduce16(pe + 16);

    // ---- expert linear: 100 outputs ----
    if (t < NC) {
        const float* lw = elw + ((size_t)e * NC + t) * ECH;
        float acc = elb[e * NC + t];
        #pragma unroll
        for (int c = 0; c < ECH; ++c) acc += pe[c] * lw[c];
        out_final[(size_t)b * NC + t] = acc;
    }
}

extern "C" void kernel_launch(void* const* d_in, const int* in_sizes, int n_in,
                              void* d_out, int out_size, void* d_ws, size_t ws_size,
                              hipStream_t stream) {
    const float* x   = (const float*)d_in[0];
    const float* gcw = (const float*)d_in[1];
    const float* gcb = (const float*)d_in[2];
    const float* glw = (const float*)d_in[3];
    const float* glb = (const float*)d_in[4];
    const float* ecw = (const float*)d_in[5];
    const float* ecb = (const float*)d_in[6];
    const float* elw = (const float*)d_in[7];
    const float* elb = (const float*)d_in[8];

    float* out_final = (float*)d_out;             // [1024,100]
    float* out_w     = (float*)d_out + NB * NC;   // [1024,8]

    hipLaunchKernelGGL(moe_fused_kernel, dim3(NB), dim3(256), 0, stream,
                       x, gcw, gcb, glw, glb, ecw, ecb, elw, elb,
                       out_final, out_w);
}

// Round 12
// 28.215 us; speedup vs baseline: 4.5098x; 1.3942x over previous
//
#include <hip/hip_runtime.h>
#include <math.h>

#define NB 1024
#define IC 3
#define HW 32
#define GCH 16
#define ECH 32
#define NE 8
#define NC 100

typedef __attribute__((ext_vector_type(8))) short bf16x8;
typedef __attribute__((ext_vector_type(4))) float f32x4;

__device__ inline short f2bf(float f) {   // RNE fp32->bf16
    unsigned u = __float_as_uint(f);
    unsigned r = (u + 0x7FFF + ((u >> 16) & 1)) >> 16;
    return (short)r;
}

// Gate: fp32 VALU conv (r11 structure) -> exact softmax/argmax.
// Expert: bf16 MFMA implicit GEMM  P[1024x27(pad32)] x We[27(pad32)x32],
//   k-labeling identical on A and B (k-permutation self-cancels), epilogue
//   relu+pool is px-permutation-invariant; only ch = lane&15 mapping matters
//   (m89-verified). A-frag buffer aliases the gate's pred LDS.
__global__ __launch_bounds__(256) void moe_fused_kernel(
    const float* __restrict__ x,     // [1024,3,32,32]
    const float* __restrict__ gcw,   // [16,3,3,3]
    const float* __restrict__ gcb,   // [16]
    const float* __restrict__ glw,   // [8,16]
    const float* __restrict__ glb,   // [8]
    const float* __restrict__ ecw,   // [8,32,3,3,3]
    const float* __restrict__ ecb,   // [8,32]
    const float* __restrict__ elw,   // [8,100,32]
    const float* __restrict__ elb,   // [8,100]
    float* __restrict__ out_final,   // [1024,100]
    float* __restrict__ out_w)       // [1024,8]
{
    __shared__ float xsw[IC * 34 * 32];   // rotated fp32 image, 13056 B
    __shared__ float predbuf[256 * 17];   // gate partials; aliased as A-frags
    __shared__ float red2[4][32];
    __shared__ float pg[GCH];
    __shared__ float pe[ECH];
    __shared__ int s_best;

    short* Afr = (short*)predbuf;         // [16 Mtiles][64 lanes][8] bf16

    const int t = threadIdx.x;
    const int b = blockIdx.x;
    const int lane = t & 63;
    const int wid = t >> 6;

    const int py = t >> 3;          // gate: output row 0..31
    const int i8 = t & 7;
    const int px0 = i8 << 2;        // gate: output col base

    // ---- zero border rows (sr=0,33) ----
    if (t < 192) {
        int ci = t / 64, r2 = (t & 63) >> 5, q = t & 31;
        xsw[ci * 1088 + (r2 == 0 ? 0 : 33) * 32 + q] = 0.f;
    }
    // ---- stage x with per-row rotation (rows sr=1..32) ----
    const float* xb = x + (size_t)b * (IC * HW * HW);
    for (int i = t; i < 768; i += 256) {
        float4 v = ((const float4*)xb)[i];
        int ci = i >> 8, rem = i & 255, row = rem >> 3, x4 = (rem & 7) << 2;
        int sr = row + 1, rot = 2 * (sr & 15);
        int base = ci * 1088 + sr * 32;
        *(float2*)&xsw[base + ((x4 + rot) & 31)]     = make_float2(v.x, v.y);
        *(float2*)&xsw[base + ((x4 + 2 + rot) & 31)] = make_float2(v.z, v.w);
    }
    __syncthreads();

    // ---- gate conv addresses ----
    int idx[3][4];
    #pragma unroll
    for (int ky = 0; ky < 3; ++ky) {
        int sr = py + ky;
        int rot = 2 * (sr & 15);
        int base = sr * 32;
        idx[ky][0] = base + ((px0 - 2 + rot) & 31);
        idx[ky][1] = base + ((px0     + rot) & 31);
        idx[ky][2] = base + ((px0 + 2 + rot) & 31);
        idx[ky][3] = base + ((px0 + 4 + rot) & 31);
    }
    const bool mask0 = (i8 > 0);
    const bool mask5 = (i8 < 7);

    auto conv8 = [&](const float* wb, const float* bp, int colbase) {
        float acc[8][4];
        #pragma unroll
        for (int c = 0; c < 8; ++c)
            acc[c][0] = acc[c][1] = acc[c][2] = acc[c][3] = 0.f;
        #pragma unroll 1
        for (int ci = 0; ci < IC; ++ci) {
            const int cio = ci * 1088;
            #pragma unroll
            for (int ky = 0; ky < 3; ++ky) {
                float2 L0 = *(const float2*)&xsw[cio + idx[ky][0]];
                float2 L1 = *(const float2*)&xsw[cio + idx[ky][1]];
                float2 L2 = *(const float2*)&xsw[cio + idx[ky][2]];
                float2 L3 = *(const float2*)&xsw[cio + idx[ky][3]];
                float o0 = mask0 ? L0.y : 0.f;
                float o1 = L1.x, o2 = L1.y, o3 = L2.x, o4 = L2.y;
                float o5 = mask5 ? L3.x : 0.f;
                const float* ws = wb + (ci * 3 + ky) * 3;
                #pragma unroll
                for (int c = 0; c < 8; ++c) {
                    float w0 = ws[c * 27 + 0];
                    float w1 = ws[c * 27 + 1];
                    float w2 = ws[c * 27 + 2];
                    acc[c][0] = fmaf(o0, w0, fmaf(o1, w1, fmaf(o2, w2, acc[c][0])));
                    acc[c][1] = fmaf(o1, w0, fmaf(o2, w1, fmaf(o3, w2, acc[c][1])));
                    acc[c][2] = fmaf(o2, w0, fmaf(o3, w1, fmaf(o4, w2, acc[c][2])));
                    acc[c][3] = fmaf(o3, w0, fmaf(o4, w1, fmaf(o5, w2, acc[c][3])));
                }
            }
        }
        #pragma unroll
        for (int c = 0; c < 8; ++c) {
            float bias = bp[c];
            predbuf[t * 17 + colbase + c] =
                fmaxf(acc[c][0] + bias, 0.f) + fmaxf(acc[c][1] + bias, 0.f) +
                fmaxf(acc[c][2] + bias, 0.f) + fmaxf(acc[c][3] + bias, 0.f);
        }
    };

    auto reduce16 = [&](float* dst) {
        const int c = t & 15, j = t >> 4;
        float v = 0.f;
        #pragma unroll
        for (int i = 0; i < 16; ++i) v += predbuf[(j * 16 + i) * 17 + c];
        v += __shfl_xor(v, 16);
        v += __shfl_xor(v, 32);
        if (lane < 16) red2[wid][lane] = v;
        __syncthreads();
        if (t < 16)
            dst[t] = (red2[0][t] + red2[1][t] + red2[2][t] + red2[3][t]) * (1.f / 1024.f);
        __syncthreads();
    };

    // ================= gate (fp32, exact) =================
    conv8(gcw, gcb, 0);
    conv8(gcw + 8 * 27, gcb + 8, 8);
    __syncthreads();
    reduce16(pg);

    if (t < NE) {
        float acc = glb[t];
        #pragma unroll
        for (int c = 0; c < GCH; ++c) acc += pg[c] * glw[t * GCH + c];
        float m = acc;
        #pragma unroll
        for (int off = 1; off < NE; off <<= 1) m = fmaxf(m, __shfl_xor(m, off));
        float ex = expf(acc - m);
        float s = ex;
        #pragma unroll
        for (int off = 1; off < NE; off <<= 1) s += __shfl_xor(s, off);
        out_w[(size_t)b * NE + t] = ex / s;
        float mv = acc; int mi = t;
        #pragma unroll
        for (int off = 1; off < NE; off <<= 1) {
            float ov = __shfl_xor(mv, off);
            int   oi = __shfl_xor(mi, off);
            if (ov > mv || (ov == mv && oi < mi)) { mv = ov; mi = oi; }
        }
        if (t == 0) s_best = mi;
    }
    __syncthreads();
    const int e = __builtin_amdgcn_readfirstlane(s_best);

    // ================= expert (bf16 MFMA) =================
    const float* ewp = ecw + (size_t)e * (ECH * 27);
    const float* ebp = ecb + (size_t)e * ECH;

    // B-fragments: n = lane&15 (channel), k = (lane>>4)*8 + r  (k>=27 -> 0)
    bf16x8 bfr0, bfr1;
    const int chl = lane & 15;
    const int kg = lane >> 4;
    #pragma unroll
    for (int r = 0; r < 8; ++r) {
        int k = kg * 8 + r;
        float w0 = (k < 27) ? ewp[chl * 27 + k]        : 0.f;
        float w1 = (k < 27) ? ewp[(16 + chl) * 27 + k] : 0.f;
        bfr0[r] = f2bf(w0);
        bfr1[r] = f2bf(w1);
    }
    const float b0 = ebp[chl];
    const float b1 = ebp[16 + chl];
    float s0 = 0.f, s1 = 0.f;

    #pragma unroll 1
    for (int g = 0; g < 4; ++g) {
        // ---- build A-fragments for px = g*256 + t ----
        const int px = g * 256 + t;
        const int ppy = px >> 5;
        const int pxc = px & 31;
        const int abase = (t >> 4) * 512 + (t & 15) * 8;   // Mtile*512 + lrow*8
        #pragma unroll
        for (int ci = 0; ci < IC; ++ci) {
            #pragma unroll
            for (int ky = 0; ky < 3; ++ky) {
                int sr = ppy + ky;
                int rot = 2 * (sr & 15);
                int base = ci * 1088 + sr * 32;
                #pragma unroll
                for (int kx = 0; kx < 3; ++kx) {
                    int col = pxc + kx - 1;
                    float v = xsw[base + ((col + rot) & 31)];
                    v = ((unsigned)col < 32u) ? v : 0.f;
                    int k = ci * 9 + ky * 3 + kx;
                    Afr[abase + (k >> 3) * 128 + (k & 7)] = f2bf(v);
                }
            }
        }
        #pragma unroll
        for (int kr = 3; kr < 8; ++kr)          // k = 27..31 pad
            Afr[abase + 384 + kr] = 0;
        __syncthreads();

        // ---- consume: wave wid handles M-tiles wid*4 .. wid*4+3 ----
        #pragma unroll
        for (int m2 = 0; m2 < 4; ++m2) {
            int mt = wid * 4 + m2;
            bf16x8 a = *(const bf16x8*)&Afr[(mt * 64 + lane) * 8];
            f32x4 z = {0.f, 0.f, 0.f, 0.f};
            f32x4 d0 = __builtin_amdgcn_mfma_f32_16x16x32_bf16(a, bfr0, z, 0, 0, 0);
            f32x4 d1 = __builtin_amdgcn_mfma_f32_16x16x32_bf16(a, bfr1, z, 0, 0, 0);
            s0 += fmaxf(d0[0] + b0, 0.f) + fmaxf(d0[1] + b0, 0.f) +
                  fmaxf(d0[2] + b0, 0.f) + fmaxf(d0[3] + b0, 0.f);
            s1 += fmaxf(d1[0] + b1, 0.f) + fmaxf(d1[1] + b1, 0.f) +
                  fmaxf(d1[2] + b1, 0.f) + fmaxf(d1[3] + b1, 0.f);
        }
        __syncthreads();   // before next group's build overwrites Afr
    }

    // ---- channel reduce: lanes with same lane&15 hold same channel ----
    {
        float v0 = s0, v1 = s1;
        v0 += __shfl_xor(v0, 16); v0 += __shfl_xor(v0, 32);
        v1 += __shfl_xor(v1, 16); v1 += __shfl_xor(v1, 32);
        if (lane < 16) { red2[wid][lane] = v0; red2[wid][lane + 16] = v1; }
    }
    __syncthreads();
    if (t < ECH)
        pe[t] = (red2[0][t] + red2[1][t] + red2[2][t] + red2[3][t]) * (1.f / 1024.f);
    __syncthreads();

    // ---- expert linear: 100 outputs ----
    if (t < NC) {
        const float* lw = elw + ((size_t)e * NC + t) * ECH;
        float acc = elb[e * NC + t];
        #pragma unroll
        for (int c = 0; c < ECH; ++c) acc += pe[c] * lw[c];
        out_final[(size_t)b * NC + t] = acc;
    }
}

extern "C" void kernel_launch(void* const* d_in, const int* in_sizes, int n_in,
                              void* d_out, int out_size, void* d_ws, size_t ws_size,
                              hipStream_t stream) {
    const float* x   = (const float*)d_in[0];
    const float* gcw = (const float*)d_in[1];
    const float* gcb = (const float*)d_in[2];
    const float* glw = (const float*)d_in[3];
    const float* glb = (const float*)d_in[4];
    const float* ecw = (const float*)d_in[5];
    const float* ecb = (const float*)d_in[6];
    const float* elw = (const float*)d_in[7];
    const float* elb = (const float*)d_in[8];

    float* out_final = (float*)d_out;             // [1024,100]
    float* out_w     = (float*)d_out + NB * NC;   // [1024,8]

    hipLaunchKernelGGL(moe_fused_kernel, dim3(NB), dim3(256), 0, stream,
                       x, gcw, gcb, glw, glb, ecw, ecb, elw, elb,
                       out_final, out_w);
}

// Round 13
// 27.648 us; speedup vs baseline: 4.6023x; 1.0205x over previous
//
#include <hip/hip_runtime.h>
#include <math.h>

#define NB 1024
#define IC 3
#define HW 32
#define GCH 16
#define ECH 32
#define NE 8
#define NC 100

typedef __attribute__((ext_vector_type(8))) short bf16x8;
typedef __attribute__((ext_vector_type(4))) float f32x4;

__device__ inline short f2bf(float f) {   // RNE fp32->bf16
    unsigned u = __float_as_uint(f);
    unsigned r = (u + 0x7FFF + ((u >> 16) & 1)) >> 16;
    return (short)r;
}

// Gate: fp32 VALU conv on rotation-swizzled LDS (exact softmax/argmax).
// Expert: bf16 MFMA implicit GEMM with A-fragments built DIRECTLY in
// registers from a padded bf16 image copy xbw[4][34][36] (plane 3 = zeros
// for k=27..31, border rows/cols zero -> no conditionals, no A-frag LDS
// round-trip, no expert-phase barriers). xbw aliases the dead gate predbuf.
__global__ __launch_bounds__(256) void moe_fused_kernel(
    const float* __restrict__ x,     // [1024,3,32,32]
    const float* __restrict__ gcw,   // [16,3,3,3]
    const float* __restrict__ gcb,   // [16]
    const float* __restrict__ glw,   // [8,16]
    const float* __restrict__ glb,   // [8]
    const float* __restrict__ ecw,   // [8,32,3,3,3]
    const float* __restrict__ ecb,   // [8,32]
    const float* __restrict__ elw,   // [8,100,32]
    const float* __restrict__ elb,   // [8,100]
    float* __restrict__ out_final,   // [1024,100]
    float* __restrict__ out_w)       // [1024,8]
{
    __shared__ float xsw[IC * 34 * 32];   // rotated fp32 image (gate)
    __shared__ float predbuf[256 * 17];   // gate partials; aliased by xbw
    __shared__ float red2[4][32];
    __shared__ float pg[GCH];
    __shared__ float pe[ECH];
    __shared__ int s_best;

    short* xbw = (short*)predbuf;         // [4][34][36] bf16, 9792 B

    const int t = threadIdx.x;
    const int b = blockIdx.x;
    const int lane = t & 63;
    const int wid = t >> 6;

    const int py = t >> 3;          // gate: output row 0..31
    const int i8 = t & 7;
    const int px0g = i8 << 2;       // gate: output col base

    // ---- zero border rows of xsw (sr=0,33) ----
    if (t < 192) {
        int ci = t / 64, r2 = (t & 63) >> 5, q = t & 31;
        xsw[ci * 1088 + (r2 == 0 ? 0 : 33) * 32 + q] = 0.f;
    }
    // ---- stage x into rotated fp32 LDS (rows sr=1..32) ----
    const float* xb = x + (size_t)b * (IC * HW * HW);
    for (int i = t; i < 768; i += 256) {
        float4 v = ((const float4*)xb)[i];
        int ci = i >> 8, rem = i & 255, row = rem >> 3, x4 = (rem & 7) << 2;
        int sr = row + 1, rot = 2 * (sr & 15);
        int base = ci * 1088 + sr * 32;
        *(float2*)&xsw[base + ((x4 + rot) & 31)]     = make_float2(v.x, v.y);
        *(float2*)&xsw[base + ((x4 + 2 + rot) & 31)] = make_float2(v.z, v.w);
    }
    __syncthreads();

    // ---- gate conv addresses (rotated layout) ----
    int idx[3][4];
    #pragma unroll
    for (int ky = 0; ky < 3; ++ky) {
        int sr = py + ky;
        int rot = 2 * (sr & 15);
        int base = sr * 32;
        idx[ky][0] = base + ((px0g - 2 + rot) & 31);
        idx[ky][1] = base + ((px0g     + rot) & 31);
        idx[ky][2] = base + ((px0g + 2 + rot) & 31);
        idx[ky][3] = base + ((px0g + 4 + rot) & 31);
    }
    const bool mask0 = (i8 > 0);
    const bool mask5 = (i8 < 7);

    auto conv8 = [&](const float* wb, const float* bp, int colbase) {
        float acc[8][4];
        #pragma unroll
        for (int c = 0; c < 8; ++c)
            acc[c][0] = acc[c][1] = acc[c][2] = acc[c][3] = 0.f;
        #pragma unroll 1
        for (int ci = 0; ci < IC; ++ci) {
            const int cio = ci * 1088;
            #pragma unroll
            for (int ky = 0; ky < 3; ++ky) {
                float2 L0 = *(const float2*)&xsw[cio + idx[ky][0]];
                float2 L1 = *(const float2*)&xsw[cio + idx[ky][1]];
                float2 L2 = *(const float2*)&xsw[cio + idx[ky][2]];
                float2 L3 = *(const float2*)&xsw[cio + idx[ky][3]];
                float o0 = mask0 ? L0.y : 0.f;
                float o1 = L1.x, o2 = L1.y, o3 = L2.x, o4 = L2.y;
                float o5 = mask5 ? L3.x : 0.f;
                const float* ws = wb + (ci * 3 + ky) * 3;
                #pragma unroll
                for (int c = 0; c < 8; ++c) {
                    float w0 = ws[c * 27 + 0];
                    float w1 = ws[c * 27 + 1];
                    float w2 = ws[c * 27 + 2];
                    acc[c][0] = fmaf(o0, w0, fmaf(o1, w1, fmaf(o2, w2, acc[c][0])));
                    acc[c][1] = fmaf(o1, w0, fmaf(o2, w1, fmaf(o3, w2, acc[c][1])));
                    acc[c][2] = fmaf(o2, w0, fmaf(o3, w1, fmaf(o4, w2, acc[c][2])));
                    acc[c][3] = fmaf(o3, w0, fmaf(o4, w1, fmaf(o5, w2, acc[c][3])));
                }
            }
        }
        #pragma unroll
        for (int c = 0; c < 8; ++c) {
            float bias = bp[c];
            predbuf[t * 17 + colbase + c] =
                fmaxf(acc[c][0] + bias, 0.f) + fmaxf(acc[c][1] + bias, 0.f) +
                fmaxf(acc[c][2] + bias, 0.f) + fmaxf(acc[c][3] + bias, 0.f);
        }
    };

    // ================= gate (fp32, exact) =================
    conv8(gcw, gcb, 0);
    conv8(gcw + 8 * 27, gcb + 8, 8);
    __syncthreads();
    // transpose-reduce predbuf -> pg[16]
    {
        const int c = t & 15, j = t >> 4;
        float v = 0.f;
        #pragma unroll
        for (int i = 0; i < 16; ++i) v += predbuf[(j * 16 + i) * 17 + c];
        v += __shfl_xor(v, 16);
        v += __shfl_xor(v, 32);
        if (lane < 16) red2[wid][lane] = v;
    }
    __syncthreads();
    if (t < GCH)
        pg[t] = (red2[0][t] + red2[1][t] + red2[2][t] + red2[3][t]) * (1.f / 1024.f);
    __syncthreads();   // pg ready; predbuf reads done -> safe to overwrite

    // ---- zero xbw (aliases predbuf): 2448 dwords ----
    for (int i = t; i < 2448; i += 256) ((int*)xbw)[i] = 0;
    __syncthreads();

    // ---- softmax/argmax (lanes 0..7) runs while others stage xbw ----
    if (t < NE) {
        float acc = glb[t];
        #pragma unroll
        for (int c = 0; c < GCH; ++c) acc += pg[c] * glw[t * GCH + c];
        float m = acc;
        #pragma unroll
        for (int off = 1; off < NE; off <<= 1) m = fmaxf(m, __shfl_xor(m, off));
        float ex = expf(acc - m);
        float s = ex;
        #pragma unroll
        for (int off = 1; off < NE; off <<= 1) s += __shfl_xor(s, off);
        out_w[(size_t)b * NE + t] = ex / s;
        float mv = acc; int mi = t;
        #pragma unroll
        for (int off = 1; off < NE; off <<= 1) {
            float ov = __shfl_xor(mv, off);
            int   oi = __shfl_xor(mi, off);
            if (ov > mv || (ov == mv && oi < mi)) { mv = ov; mi = oi; }
        }
        if (t == 0) s_best = mi;
    }
    // ---- stage xbw from xsw (rotated fp32 -> padded bf16) ----
    for (int i = t; i < 3264; i += 256) {
        int ci = i / 1088, rem = i - ci * 1088, sr = rem >> 5, pc = rem & 31;
        int c = (pc - 2 * (sr & 15)) & 31;
        xbw[ci * 1224 + sr * 36 + c + 1] = f2bf(xsw[i]);
    }
    __syncthreads();
    const int e = __builtin_amdgcn_readfirstlane(s_best);

    // ================= expert (bf16 MFMA, register A-frags) =================
    const float* ewp = ecw + (size_t)e * (ECH * 27);
    const float* ebp = ecb + (size_t)e * ECH;

    const int r15 = lane & 15;
    const int kg = lane >> 4;

    // B-fragments: n = lane&15 (channel), k = kg*8 + r  (k>=27 -> 0)
    bf16x8 bfr0, bfr1;
    #pragma unroll
    for (int r = 0; r < 8; ++r) {
        int k = kg * 8 + r;
        float w0 = (k < 27) ? ewp[r15 * 27 + k]        : 0.f;
        float w1 = (k < 27) ? ewp[(16 + r15) * 27 + k] : 0.f;
        bfr0[r] = f2bf(w0);
        bfr1[r] = f2bf(w1);
    }
    const float b0 = ebp[r15];
    const float b1 = ebp[16 + r15];

    // per-lane constant offsets: off[r] = ci*1224 + ky*36 + kx (plane3=zeros)
    int off[8];
    #pragma unroll
    for (int r = 0; r < 8; ++r) {
        int k = kg * 8 + r;
        int ci = (k < 27) ? (k / 9) : 3;
        int r9 = (k < 27) ? (k - 9 * ci) : 0;
        int ky = r9 / 3;
        int kx = r9 - 3 * ky;
        off[r] = ci * 1224 + ky * 36 + kx;
    }

    float s0 = 0.f, s1 = 0.f;
    #pragma unroll 2
    for (int m = 0; m < 16; ++m) {
        int px = (wid << 8) + (m << 4) + r15;
        int ppy = px >> 5, pxc = px & 31;
        int base = ppy * 36 + pxc;
        bf16x8 a;
        #pragma unroll
        for (int r = 0; r < 8; ++r)
            a[r] = xbw[base + off[r]];
        f32x4 z = {0.f, 0.f, 0.f, 0.f};
        f32x4 d0 = __builtin_amdgcn_mfma_f32_16x16x32_bf16(a, bfr0, z, 0, 0, 0);
        f32x4 d1 = __builtin_amdgcn_mfma_f32_16x16x32_bf16(a, bfr1, z, 0, 0, 0);
        s0 += fmaxf(d0[0] + b0, 0.f) + fmaxf(d0[1] + b0, 0.f) +
              fmaxf(d0[2] + b0, 0.f) + fmaxf(d0[3] + b0, 0.f);
        s1 += fmaxf(d1[0] + b1, 0.f) + fmaxf(d1[1] + b1, 0.f) +
              fmaxf(d1[2] + b1, 0.f) + fmaxf(d1[3] + b1, 0.f);
    }

    // ---- channel reduce across kg groups ----
    {
        float v0 = s0, v1 = s1;
        v0 += __shfl_xor(v0, 16); v0 += __shfl_xor(v0, 32);
        v1 += __shfl_xor(v1, 16); v1 += __shfl_xor(v1, 32);
        if (lane < 16) { red2[wid][lane] = v0; red2[wid][lane + 16] = v1; }
    }
    __syncthreads();
    if (t < ECH)
        pe[t] = (red2[0][t] + red2[1][t] + red2[2][t] + red2[3][t]) * (1.f / 1024.f);
    __syncthreads();

    // ---- expert linear: 100 outputs ----
    if (t < NC) {
        const float* lw = elw + ((size_t)e * NC + t) * ECH;
        float acc = elb[e * NC + t];
        #pragma unroll
        for (int c = 0; c < ECH; ++c) acc += pe[c] * lw[c];
        out_final[(size_t)b * NC + t] = acc;
    }
}

extern "C" void kernel_launch(void* const* d_in, const int* in_sizes, int n_in,
                              void* d_out, int out_size, void* d_ws, size_t ws_size,
                              hipStream_t stream) {
    const float* x   = (const float*)d_in[0];
    const float* gcw = (const float*)d_in[1];
    const float* gcb = (const float*)d_in[2];
    const float* glw = (const float*)d_in[3];
    const float* glb = (const float*)d_in[4];
    const float* ecw = (const float*)d_in[5];
    const float* ecb = (const float*)d_in[6];
    const float* elw = (const float*)d_in[7];
    const float* elb = (const float*)d_in[8];

    float* out_final = (float*)d_out;             // [1024,100]
    float* out_w     = (float*)d_out + NB * NC;   // [1024,8]

    hipLaunchKernelGGL(moe_fused_kernel, dim3(NB), dim3(256), 0, stream,
                       x, gcw, gcb, glw, glb, ecw, ecb, elw, elb,
                       out_final, out_w);
}

// Round 14
// 21.850 us; speedup vs baseline: 5.8235x; 1.2654x over previous
//
#include <hip/hip_runtime.h>
#include <math.h>

#define NB 1024
#define IC 3
#define HW 32
#define GCH 16
#define ECH 32
#define NE 8
#define NC 100

#define PS 1292          // plane stride (34*38) in shorts
#define RS 38            // row stride in shorts
#define NSH 5168         // shorts per image (4*PS)

typedef __attribute__((ext_vector_type(8))) short bf16x8;
typedef __attribute__((ext_vector_type(4))) float f32x4;

__device__ inline short f2bf(float f) {   // RNE fp32->bf16
    unsigned u = __float_as_uint(f);
    unsigned r = (u + 0x7FFF + ((u >> 16) & 1)) >> 16;
    return (short)r;
}
__device__ inline float bf2f(short h) {
    return __uint_as_float(((unsigned)(unsigned short)h) << 16);
}

// Everything on MFMA. Gate conv uses hi/lo bf16 split (3 chained MFMAs):
//   x*w ~= xh*wh + xh*wl + xl*wh, error ~2^-18 -> argmax-safe (~1e-5 logit).
// Expert conv uses hi only (r13-identical arithmetic, absmax 0.0078).
// Image stored as two padded bf16 planes xbw_hi/lo[4][34][38]: plane 3 and
// all borders zero -> k=27..31 pad and halo reads need no conditionals.
__global__ __launch_bounds__(256) void moe_fused_kernel(
    const float* __restrict__ x,     // [1024,3,32,32]
    const float* __restrict__ gcw,   // [16,3,3,3]
    const float* __restrict__ gcb,   // [16]
    const float* __restrict__ glw,   // [8,16]
    const float* __restrict__ glb,   // [8]
    const float* __restrict__ ecw,   // [8,32,3,3,3]
    const float* __restrict__ ecb,   // [8,32]
    const float* __restrict__ elw,   // [8,100,32]
    const float* __restrict__ elb,   // [8,100]
    float* __restrict__ out_final,   // [1024,100]
    float* __restrict__ out_w)       // [1024,8]
{
    __shared__ __align__(16) short xb2[2 * NSH];   // hi | lo, 20672 B
    __shared__ float red2[4][32];
    __shared__ float pg[GCH];
    __shared__ float pe[ECH];
    __shared__ int s_best;

    short* xh = xb2;
    short* xl = xb2 + NSH;

    const int t = threadIdx.x;
    const int b = blockIdx.x;
    const int lane = t & 63;
    const int wid = t >> 6;
    const int r15 = lane & 15;
    const int kg = lane >> 4;

    // ---- zero both planes (borders + plane3 stay zero) ----
    {
        int4* p = (int4*)xb2;
        #pragma unroll
        for (int i = 0; i < 6; ++i) {
            int j = t + i * 256;
            if (j < 1292) p[j] = make_int4(0, 0, 0, 0);
        }
    }

    // ---- gate B-fragments (hi+lo), k = kg*8+r, ch = r15 ----
    bf16x8 gbh, gbl;
    #pragma unroll
    for (int r = 0; r < 8; ++r) {
        int k = kg * 8 + r;
        float w = (k < 27) ? gcw[r15 * 27 + k] : 0.f;
        short h = f2bf(w);
        gbh[r] = h;
        gbl[r] = f2bf(w - bf2f(h));
    }
    const float gb = gcb[r15];

    __syncthreads();

    // ---- stage x -> hi/lo bf16 planes ----
    const float* xb = x + (size_t)b * (IC * HW * HW);
    #pragma unroll
    for (int i3 = 0; i3 < 3; ++i3) {
        int i = t + i3 * 256;
        float4 v = ((const float4*)xb)[i];
        int ci = i >> 8, rem = i & 255, row = rem >> 3, x4 = (rem & 7) << 2;
        int base = ci * PS + (row + 1) * RS + x4 + 2;   // even
        short h0 = f2bf(v.x), h1 = f2bf(v.y), h2 = f2bf(v.z), h3 = f2bf(v.w);
        short l0 = f2bf(v.x - bf2f(h0)), l1 = f2bf(v.y - bf2f(h1));
        short l2 = f2bf(v.z - bf2f(h2)), l3 = f2bf(v.w - bf2f(h3));
        int* dh = (int*)&xh[base];
        int* dl = (int*)&xl[base];
        dh[0] = (unsigned short)h0 | ((unsigned)(unsigned short)h1 << 16);
        dh[1] = (unsigned short)h2 | ((unsigned)(unsigned short)h3 << 16);
        dl[0] = (unsigned short)l0 | ((unsigned)(unsigned short)l1 << 16);
        dl[1] = (unsigned short)l2 | ((unsigned)(unsigned short)l3 << 16);
    }

    // ---- per-lane tap offsets (shorts): k -> (ci,ky,kx), plane3 = zeros ----
    int off[8];
    #pragma unroll
    for (int r = 0; r < 8; ++r) {
        int k = kg * 8 + r;
        int ci = (k < 27) ? (k / 9) : 3;
        int r9 = (k < 27) ? (k - 9 * ci) : 0;
        int ky = r9 / 3;
        int kx = r9 - 3 * ky;
        off[r] = ci * PS + ky * RS + kx + 1;
    }

    __syncthreads();

    // ================= gate pass (hi/lo MFMA) =================
    float sg = 0.f;
    #pragma unroll 2
    for (int m = 0; m < 16; ++m) {
        int px = (wid << 8) + (m << 4) + r15;
        int base = (px >> 5) * RS + (px & 31);
        bf16x8 ah, al;
        #pragma unroll
        for (int r = 0; r < 8; ++r) {
            ah[r] = xh[base + off[r]];
            al[r] = xl[base + off[r]];
        }
        f32x4 d = {0.f, 0.f, 0.f, 0.f};
        d = __builtin_amdgcn_mfma_f32_16x16x32_bf16(al, gbh, d, 0, 0, 0);
        d = __builtin_amdgcn_mfma_f32_16x16x32_bf16(ah, gbl, d, 0, 0, 0);
        d = __builtin_amdgcn_mfma_f32_16x16x32_bf16(ah, gbh, d, 0, 0, 0);
        sg += fmaxf(d[0] + gb, 0.f) + fmaxf(d[1] + gb, 0.f) +
              fmaxf(d[2] + gb, 0.f) + fmaxf(d[3] + gb, 0.f);
    }
    // reduce: 4 kg-lanes per channel -> red2, then cross-wave
    {
        float v = sg;
        v += __shfl_xor(v, 16);
        v += __shfl_xor(v, 32);
        if (lane < 16) red2[wid][lane] = v;
    }
    __syncthreads();
    if (t < GCH)
        pg[t] = (red2[0][t] + red2[1][t] + red2[2][t] + red2[3][t]) * (1.f / 1024.f);
    __syncthreads();

    // ---- gate linear + softmax + argmax (lanes 0..7) ----
    if (t < NE) {
        float acc = glb[t];
        #pragma unroll
        for (int c = 0; c < GCH; ++c) acc += pg[c] * glw[t * GCH + c];
        float m = acc;
        #pragma unroll
        for (int off2 = 1; off2 < NE; off2 <<= 1) m = fmaxf(m, __shfl_xor(m, off2));
        float ex = expf(acc - m);
        float s = ex;
        #pragma unroll
        for (int off2 = 1; off2 < NE; off2 <<= 1) s += __shfl_xor(s, off2);
        out_w[(size_t)b * NE + t] = ex / s;
        float mv = acc; int mi = t;
        #pragma unroll
        for (int off2 = 1; off2 < NE; off2 <<= 1) {
            float ov = __shfl_xor(mv, off2);
            int   oi = __shfl_xor(mi, off2);
            if (ov > mv || (ov == mv && oi < mi)) { mv = ov; mi = oi; }
        }
        if (t == 0) s_best = mi;
    }
    __syncthreads();
    const int e = __builtin_amdgcn_readfirstlane(s_best);

    // ================= expert pass (hi-only MFMA, r13 arithmetic) =========
    const float* ewp = ecw + (size_t)e * (ECH * 27);
    const float* ebp = ecb + (size_t)e * ECH;

    bf16x8 bfr0, bfr1;
    #pragma unroll
    for (int r = 0; r < 8; ++r) {
        int k = kg * 8 + r;
        bfr0[r] = f2bf((k < 27) ? ewp[r15 * 27 + k] : 0.f);
        bfr1[r] = f2bf((k < 27) ? ewp[(16 + r15) * 27 + k] : 0.f);
    }
    const float b0 = ebp[r15];
    const float b1 = ebp[16 + r15];

    float s0 = 0.f, s1 = 0.f;
    #pragma unroll 2
    for (int m = 0; m < 16; ++m) {
        int px = (wid << 8) + (m << 4) + r15;
        int base = (px >> 5) * RS + (px & 31);
        bf16x8 a;
        #pragma unroll
        for (int r = 0; r < 8; ++r) a[r] = xh[base + off[r]];
        f32x4 z = {0.f, 0.f, 0.f, 0.f};
        f32x4 d0 = __builtin_amdgcn_mfma_f32_16x16x32_bf16(a, bfr0, z, 0, 0, 0);
        f32x4 d1 = __builtin_amdgcn_mfma_f32_16x16x32_bf16(a, bfr1, z, 0, 0, 0);
        s0 += fmaxf(d0[0] + b0, 0.f) + fmaxf(d0[1] + b0, 0.f) +
              fmaxf(d0[2] + b0, 0.f) + fmaxf(d0[3] + b0, 0.f);
        s1 += fmaxf(d1[0] + b1, 0.f) + fmaxf(d1[1] + b1, 0.f) +
              fmaxf(d1[2] + b1, 0.f) + fmaxf(d1[3] + b1, 0.f);
    }
    {
        float v0 = s0, v1 = s1;
        v0 += __shfl_xor(v0, 16); v0 += __shfl_xor(v0, 32);
        v1 += __shfl_xor(v1, 16); v1 += __shfl_xor(v1, 32);
        if (lane < 16) { red2[wid][lane] = v0; red2[wid][lane + 16] = v1; }
    }
    __syncthreads();
    if (t < ECH)
        pe[t] = (red2[0][t] + red2[1][t] + red2[2][t] + red2[3][t]) * (1.f / 1024.f);
    __syncthreads();

    // ---- expert linear: 100 outputs ----
    if (t < NC) {
        const float* lw = elw + ((size_t)e * NC + t) * ECH;
        float acc = elb[e * NC + t];
        #pragma unroll
        for (int c = 0; c < ECH; ++c) acc += pe[c] * lw[c];
        out_final[(size_t)b * NC + t] = acc;
    }
}

extern "C" void kernel_launch(void* const* d_in, const int* in_sizes, int n_in,
                              void* d_out, int out_size, void* d_ws, size_t ws_size,
                              hipStream_t stream) {
    const float* x   = (const float*)d_in[0];
    const float* gcw = (const float*)d_in[1];
    const float* gcb = (const float*)d_in[2];
    const float* glw = (const float*)d_in[3];
    const float* glb = (const float*)d_in[4];
    const float* ecw = (const float*)d_in[5];
    const float* ecb = (const float*)d_in[6];
    const float* elw = (const float*)d_in[7];
    const float* elb = (const float*)d_in[8];

    float* out_final = (float*)d_out;             // [1024,100]
    float* out_w     = (float*)d_out + NB * NC;   // [1024,8]

    hipLaunchKernelGGL(moe_fused_kernel, dim3(NB), dim3(256), 0, stream,
                       x, gcw, gcb, glw, glb, ecw, ecb, elw, elb,
                       out_final, out_w);
}

// Round 15
// 19.889 us; speedup vs baseline: 6.3975x; 1.0986x over previous
//
#include <hip/hip_runtime.h>
#include <math.h>

#define NB 1024
#define IC 3
#define HW 32
#define GCH 16
#define ECH 32
#define NE 8
#define NC 100

#define RS 38            // row stride in texels
#define PS 1292          // plane stride (34*38) texels
#define NTX 3876         // total texels (3 planes)

typedef __attribute__((ext_vector_type(8))) short bf16x8;
typedef __attribute__((ext_vector_type(4))) int   int4v;
typedef __attribute__((ext_vector_type(4))) float f32x4;

__device__ inline short f2bf(float f) {   // RNE fp32->bf16
    unsigned u = __float_as_uint(f);
    unsigned r = (u + 0x7FFF + ((u >> 16) & 1)) >> 16;
    return (short)r;
}
__device__ inline float bf2f(short h) {
    return __uint_as_float(((unsigned)(unsigned short)h) << 16);
}

// Image stored as interleaved (hi,lo) bf16 TEXELS: one int per pixel =
// hi | lo<<16, layout [3][34][38]. Every texel 4B-aligned -> gate fragment
// = 8 ds_read_b32 (hi+lo together, v_perm unpack) instead of 16 u16;
// expert = 8 ds_read_u16 on the hi halves. k>=27 pad taps read in-bounds
// garbage (B-side weight is 0 there) -> no zero plane needed.
// Gate conv: hi/lo bf16 split (3 MFMAs) -> argmax-exact (~1e-5 logit err).
// Expert conv: hi-only (2 MFMAs), bit-identical to r13/r14 (absmax 0.0078).
__global__ __launch_bounds__(256) void moe_fused_kernel(
    const float* __restrict__ x,     // [1024,3,32,32]
    const float* __restrict__ gcw,   // [16,3,3,3]
    const float* __restrict__ gcb,   // [16]
    const float* __restrict__ glw,   // [8,16]
    const float* __restrict__ glb,   // [8]
    const float* __restrict__ ecw,   // [8,32,3,3,3]
    const float* __restrict__ ecb,   // [8,32]
    const float* __restrict__ elw,   // [8,100,32]
    const float* __restrict__ elb,   // [8,100]
    float* __restrict__ out_final,   // [1024,100]
    float* __restrict__ out_w)       // [1024,8]
{
    __shared__ __align__(16) int xil[NTX];   // 15.5 KB
    __shared__ float red2[4][32];
    __shared__ float pg[GCH];
    __shared__ float pe[ECH];
    __shared__ int s_best;

    const int t = threadIdx.x;
    const int b = blockIdx.x;
    const int lane = t & 63;
    const int wid = t >> 6;
    const int r15 = lane & 15;
    const int kg = lane >> 4;

    // ---- zero all texels (borders stay zero) ----
    for (int i = t; i < NTX / 4; i += 256) ((int4*)xil)[i] = make_int4(0, 0, 0, 0);

    // ---- gate B-fragments (hi+lo), k = kg*8+r, ch = r15 ----
    bf16x8 gbh, gbl;
    #pragma unroll
    for (int r = 0; r < 8; ++r) {
        int k = kg * 8 + r;
        float w = (k < 27) ? gcw[r15 * 27 + k] : 0.f;
        short h = f2bf(w);
        gbh[r] = h;
        gbl[r] = f2bf(w - bf2f(h));
    }
    const float gb = gcb[r15];

    __syncthreads();

    // ---- stage x -> interleaved texels (cols shifted +2: b64-aligned) ----
    const float* xb = x + (size_t)b * (IC * HW * HW);
    #pragma unroll
    for (int i3 = 0; i3 < 3; ++i3) {
        int i = t + i3 * 256;
        float4 v = ((const float4*)xb)[i];
        int ci = i >> 8, rem = i & 255, row = rem >> 3, x4 = (rem & 7) << 2;
        int T = ci * PS + (row + 1) * RS + x4 + 2;   // even texel index
        short h0 = f2bf(v.x), h1 = f2bf(v.y), h2 = f2bf(v.z), h3 = f2bf(v.w);
        int t0 = (unsigned short)h0 | ((unsigned)(unsigned short)f2bf(v.x - bf2f(h0)) << 16);
        int t1 = (unsigned short)h1 | ((unsigned)(unsigned short)f2bf(v.y - bf2f(h1)) << 16);
        int t2 = (unsigned short)h2 | ((unsigned)(unsigned short)f2bf(v.z - bf2f(h2)) << 16);
        int t3 = (unsigned short)h3 | ((unsigned)(unsigned short)f2bf(v.w - bf2f(h3)) << 16);
        *(int2*)&xil[T]     = make_int2(t0, t1);
        *(int2*)&xil[T + 2] = make_int2(t2, t3);
    }

    // ---- per-lane tap offsets (texels); k>=27 -> 0 (garbage ok, B=0) ----
    int off[8];
    #pragma unroll
    for (int r = 0; r < 8; ++r) {
        int k = kg * 8 + r;
        int ci = (k < 27) ? (k / 9) : 0;
        int r9 = (k < 27) ? (k - 9 * ci) : 0;
        int ky = r9 / 3;
        int kx = r9 - 3 * ky;
        off[r] = (k < 27) ? (ci * PS + ky * RS + kx + 1) : 0;
    }

    __syncthreads();

    // ================= gate pass (hi/lo MFMA) =================
    float sg = 0.f;
    #pragma unroll 2
    for (int m = 0; m < 16; ++m) {
        int px = (wid << 8) + (m << 4) + r15;
        int base = (px >> 5) * RS + (px & 31);
        int T0 = xil[base + off[0]], T1 = xil[base + off[1]];
        int T2 = xil[base + off[2]], T3 = xil[base + off[3]];
        int T4 = xil[base + off[4]], T5 = xil[base + off[5]];
        int T6 = xil[base + off[6]], T7 = xil[base + off[7]];
        int4v ahd = { (int)__builtin_amdgcn_perm(T1, T0, 0x05040100u),
                      (int)__builtin_amdgcn_perm(T3, T2, 0x05040100u),
                      (int)__builtin_amdgcn_perm(T5, T4, 0x05040100u),
                      (int)__builtin_amdgcn_perm(T7, T6, 0x05040100u) };
        int4v ald = { (int)__builtin_amdgcn_perm(T1, T0, 0x07060302u),
                      (int)__builtin_amdgcn_perm(T3, T2, 0x07060302u),
                      (int)__builtin_amdgcn_perm(T5, T4, 0x07060302u),
                      (int)__builtin_amdgcn_perm(T7, T6, 0x07060302u) };
        bf16x8 ah = __builtin_bit_cast(bf16x8, ahd);
        bf16x8 al = __builtin_bit_cast(bf16x8, ald);
        f32x4 d = {0.f, 0.f, 0.f, 0.f};
        d = __builtin_amdgcn_mfma_f32_16x16x32_bf16(al, gbh, d, 0, 0, 0);
        d = __builtin_amdgcn_mfma_f32_16x16x32_bf16(ah, gbl, d, 0, 0, 0);
        d = __builtin_amdgcn_mfma_f32_16x16x32_bf16(ah, gbh, d, 0, 0, 0);
        sg += fmaxf(d[0] + gb, 0.f) + fmaxf(d[1] + gb, 0.f) +
              fmaxf(d[2] + gb, 0.f) + fmaxf(d[3] + gb, 0.f);
    }
    {
        float v = sg;
        v += __shfl_xor(v, 16);
        v += __shfl_xor(v, 32);
        if (lane < 16) red2[wid][lane] = v;
    }
    __syncthreads();
    if (t < GCH)
        pg[t] = (red2[0][t] + red2[1][t] + red2[2][t] + red2[3][t]) * (1.f / 1024.f);
    __syncthreads();

    // ---- gate linear + softmax + argmax (lanes 0..7) ----
    if (t < NE) {
        float acc = glb[t];
        #pragma unroll
        for (int c = 0; c < GCH; ++c) acc += pg[c] * glw[t * GCH + c];
        float m = acc;
        #pragma unroll
        for (int o = 1; o < NE; o <<= 1) m = fmaxf(m, __shfl_xor(m, o));
        float ex = expf(acc - m);
        float s = ex;
        #pragma unroll
        for (int o = 1; o < NE; o <<= 1) s += __shfl_xor(s, o);
        out_w[(size_t)b * NE + t] = ex / s;
        float mv = acc; int mi = t;
        #pragma unroll
        for (int o = 1; o < NE; o <<= 1) {
            float ov = __shfl_xor(mv, o);
            int   oi = __shfl_xor(mi, o);
            if (ov > mv || (ov == mv && oi < mi)) { mv = ov; mi = oi; }
        }
        if (t == 0) s_best = mi;
    }
    __syncthreads();
    const int e = __builtin_amdgcn_readfirstlane(s_best);

    // ================= expert pass (hi-only MFMA) =================
    const float* ewp = ecw + (size_t)e * (ECH * 27);
    const float* ebp = ecb + (size_t)e * ECH;

    bf16x8 bfr0, bfr1;
    #pragma unroll
    for (int r = 0; r < 8; ++r) {
        int k = kg * 8 + r;
        bfr0[r] = f2bf((k < 27) ? ewp[r15 * 27 + k] : 0.f);
        bfr1[r] = f2bf((k < 27) ? ewp[(16 + r15) * 27 + k] : 0.f);
    }
    const float b0 = ebp[r15];
    const float b1 = ebp[16 + r15];

    const short* xs16 = (const short*)xil;
    float s0 = 0.f, s1 = 0.f;
    #pragma unroll 2
    for (int m = 0; m < 16; ++m) {
        int px = (wid << 8) + (m << 4) + r15;
        int base = (px >> 5) * RS + (px & 31);
        bf16x8 a;
        #pragma unroll
        for (int r = 0; r < 8; ++r)
            a[r] = xs16[2 * (base + off[r])];   // hi half of texel
        f32x4 z = {0.f, 0.f, 0.f, 0.f};
        f32x4 d0 = __builtin_amdgcn_mfma_f32_16x16x32_bf16(a, bfr0, z, 0, 0, 0);
        f32x4 d1 = __builtin_amdgcn_mfma_f32_16x16x32_bf16(a, bfr1, z, 0, 0, 0);
        s0 += fmaxf(d0[0] + b0, 0.f) + fmaxf(d0[1] + b0, 0.f) +
              fmaxf(d0[2] + b0, 0.f) + fmaxf(d0[3] + b0, 0.f);
        s1 += fmaxf(d1[0] + b1, 0.f) + fmaxf(d1[1] + b1, 0.f) +
              fmaxf(d1[2] + b1, 0.f) + fmaxf(d1[3] + b1, 0.f);
    }
    {
        float v0 = s0, v1 = s1;
        v0 += __shfl_xor(v0, 16); v0 += __shfl_xor(v0, 32);
        v1 += __shfl_xor(v1, 16); v1 += __shfl_xor(v1, 32);
        if (lane < 16) { red2[wid][lane] = v0; red2[wid][lane + 16] = v1; }
    }
    __syncthreads();
    if (t < ECH)
        pe[t] = (red2[0][t] + red2[1][t] + red2[2][t] + red2[3][t]) * (1.f / 1024.f);
    __syncthreads();

    // ---- expert linear: 100 outputs ----
    if (t < NC) {
        const float* lw = elw + ((size_t)e * NC + t) * ECH;
        float acc = elb[e * NC + t];
        #pragma unroll
        for (int c = 0; c < ECH; ++c) acc += pe[c] * lw[c];
        out_final[(size_t)b * NC + t] = acc;
    }
}

extern "C" void kernel_launch(void* const* d_in, const int* in_sizes, int n_in,
                              void* d_out, int out_size, void* d_ws, size_t ws_size,
                              hipStream_t stream) {
    const float* x   = (const float*)d_in[0];
    const float* gcw = (const float*)d_in[1];
    const float* gcb = (const float*)d_in[2];
    const float* glw = (const float*)d_in[3];
    const float* glb = (const float*)d_in[4];
    const float* ecw = (const float*)d_in[5];
    const float* ecb = (const float*)d_in[6];
    const float* elw = (const float*)d_in[7];
    const float* elb = (const float*)d_in[8];

    float* out_final = (float*)d_out;             // [1024,100]
    float* out_w     = (float*)d_out + NB * NC;   // [1024,8]

    hipLaunchKernelGGL(moe_fused_kernel, dim3(NB), dim3(256), 0, stream,
                       x, gcw, gcb, glw, glb, ecw, ecb, elw, elb,
                       out_final, out_w);
}